// Round 9
// baseline (311.585 us; speedup 1.0000x reference)
//
#include <hip/hip_runtime.h>

#define EPSV 1e-5f
#define INV28 (1.f / 3211264.f)
#define INV14 (1.f / 802816.f)
#define INV11 (1.f / 495616.f)
// BN-stats shadow copies: 64. Writers: atomicAdd into copy (blockIdx & 63) ->
// per-line RMW pressure cut 8x vs 8 copies (R7 lesson: far atomics serialize
// per cache line, ~5-12ns each; 8 copies cost ~24us per thin tail dispatch).
// Readers: PLAIN unrolled loads (R8 lesson: rolled atomic loads before the
// first barrier cost the band ~18us; dispatch boundary already orders).
#define NCOPY 64
#define LSTRIDE 2048   // floats per layer stats region (NCOPY*32)

typedef _Float16 v8h __attribute__((ext_vector_type(8)));
typedef _Float16 v4h __attribute__((ext_vector_type(4)));
typedef _Float16 v2h __attribute__((ext_vector_type(2)));
typedef float v4f __attribute__((ext_vector_type(4)));

__device__ __forceinline__ int h2i(v2h v) { union { v2h h; int i; } u; u.h = v; return u.i; }
__device__ __forceinline__ v2h i2h(int i) { union { v2h h; int i; } u; u.i = i; return u.h; }
__device__ __forceinline__ int pmax2(int a, int b) {
  v2h x = i2h(a), y = i2h(b), r;
  r[0] = x[0] > y[0] ? x[0] : y[0];
  r[1] = x[1] > y[1] ? x[1] : y[1];
  return h2i(r);
}

// rot90 applied r times CCW (np.rot90 semantics): out[dy][dx] = m[sy][sx]
__device__ __forceinline__ int rotsrc(int r, int dy, int dx, int K) {
  int sy, sx;
  if (r == 0)      { sy = dy;       sx = dx; }
  else if (r == 1) { sy = dx;       sx = K - 1 - dy; }
  else if (r == 2) { sy = K - 1 - dy; sx = K - 1 - dx; }
  else             { sy = K - 1 - dx; sx = dy; }
  return sy * K + sx;
}

// P4 weight expansion: value for output channel oc, k-group g, index j.
// g = (tap, ci-group-of-8): tap = g/5, ci = (g%5)*8+j.
__device__ __forceinline__ float gw_val(const float* __restrict__ w, int oc, int g,
                                        int j, int KS) {
  int tap = g / 5, cig = g % 5, ci = cig * 8 + j;
  int co = oc >> 2, r = oc & 3, cin = ci >> 2, s = ci & 3;
  int srel = (s - r) & 3;
  return w[((co * 10 + cin) * 4 + srel) * (KS * KS) + rotsrc(r, tap / KS, tap % KS, KS)];
}

// stats read: written by a PREVIOUS dispatch (ordering via launch boundary),
// so plain loads suffice. Unrolled -> all 64 loads in flight, one wait.
__device__ __forceinline__ float statN(const float* __restrict__ p, int i) {
  float v = 0.f;
#pragma unroll
  for (int c = 0; c < NCOPY; ++c) v += p[c * 32 + i];
  return v;
}

// Zero stats (7 layers x NCOPY copies x 32) + conv1 MFMA A-table
// K1h[mt(3)][lane(64)][j(8)] (fp16, K=32 zero-padded, taps 0..8) + MFMA fp16
// weight tables [mt(3)][c(NC)][q(4)][ocl(16)][j(8)].
// NOTE (R4-R6 lesson): software grid barriers on this chip cost ~37us/phase
// regardless of contention structure (tested: single word, 32-way tree,
// line-padded hierarchical). Kernel launch boundaries are CHEAPER (~3-5us) and
// give the same grid-wide ordering -> tail stays split per BN layer.
__global__ void prep_kernel(const float* __restrict__ w1, const float* __restrict__ w2,
                            const float* __restrict__ w3, const float* __restrict__ w4,
                            const float* __restrict__ w5, const float* __restrict__ w6,
                            const float* __restrict__ w7,
                            _Float16* __restrict__ K1h, _Float16* __restrict__ Wh,
                            float* __restrict__ stats) {
  int idx = blockIdx.x * blockDim.x + threadIdx.x;
  if (idx < 7 * LSTRIDE) { stats[idx] = 0.f; return; }
  idx -= 7 * LSTRIDE;
  if (idx < 1536) { // conv1 lifted weights in MFMA A-fragment layout
    int mt = idx >> 9, l = (idx >> 3) & 63, j = idx & 7;
    int m = l & 15, quad = l >> 4;
    int k = quad * 8 + j, oc = mt * 16 + m;
    float val = 0.f;
    if (k < 9 && oc < 40) {
      int c = oc >> 2, r = oc & 3;
      val = w1[c * 9 + rotsrc(r, k / 3, k % 3, 3)];
    }
    K1h[idx] = (_Float16)val;
    return;
  }
  idx -= 1536;
  if (idx < 92160) { // conv2..conv6: 5 layers x [3][12][4][16][8]
    int l = idx / 18432, r0 = idx % 18432;
    const float* w = (l == 0) ? w2 : (l == 1) ? w3 : (l == 2) ? w4 : (l == 3) ? w5 : w6;
    int mt = r0 / 6144, r1 = r0 % 6144;
    int c = r1 / 512, r2 = r1 % 512;
    int q = r2 / 128, r3 = r2 % 128;
    int ocl = r3 / 8, j = r3 % 8;
    int oc = mt * 16 + ocl, g = c * 4 + q;
    float val = 0.f;
    if (oc < 40 && g < 45) val = gw_val(w, oc, g, j, 3);
    Wh[idx] = (_Float16)val;
    return;
  }
  idx -= 92160;
  if (idx < 30720) { // conv7: [3][20][4][16][8]
    int mt = idx / 10240, r1 = idx % 10240;
    int c = r1 / 512, r2 = r1 % 512;
    int q = r2 / 128, r3 = r2 % 128;
    int ocl = r3 / 8, j = r3 % 8;
    int oc = mt * 16 + ocl, g = c * 4 + q;
    float val = 0.f;
    if (oc < 40) val = gw_val(w7, oc, g, j, 4);
    Wh[92160 + idx] = (_Float16)val;
  }
}

// ---------------- conv1 stats only (MFMA, no activation materialized) ----------------
__global__ __launch_bounds__(256) void conv1_stats(
    const float* __restrict__ x, const _Float16* __restrict__ K1h,
    float* __restrict__ stats) {
  __shared__ float ximg[900];
  __shared__ float sstat[20];
  const int tid = threadIdx.x, img = blockIdx.x;
  if (tid < 20) sstat[tid] = 0.f;
  for (int i = tid; i < 900; i += 256) {
    int gy = i / 30 - 1, gx = i % 30 - 1;
    ximg[i] = (gy >= 0 && gy < 28 && gx >= 0 && gx < 28)
                  ? x[img * 784 + gy * 28 + gx] : 0.f;
  }
  __syncthreads();
  const int lane = tid & 63, wv = tid >> 6;
  const int m = lane & 15, quad = lane >> 4;
  v8h a1[3];
#pragma unroll
  for (int mt = 0; mt < 3; ++mt)
    a1[mt] = *(const v8h*)(K1h + (mt * 64 + lane) * 8);
  float s[3] = {0.f, 0.f, 0.f}, q[3] = {0.f, 0.f, 0.f};
  for (int st = wv; st < 49; st += 4) {   // 784 = 49 x 16 pixels, exact
    const int p = st * 16 + m;
    const int y = p / 28, xx = p % 28;
    v8h b;
#pragma unroll
    for (int j = 0; j < 8; ++j) {
      const int t = quad * 8 + j;
      float v = 0.f;
      if (t < 9) v = ximg[(y + t / 3) * 30 + xx + t % 3];
      b[j] = (_Float16)v;
    }
#pragma unroll
    for (int mt = 0; mt < 3; ++mt) {
      v4f acc = {0.f, 0.f, 0.f, 0.f};
      acc = __builtin_amdgcn_mfma_f32_16x16x32_f16(a1[mt], b, acc, 0, 0, 0);
#pragma unroll
      for (int r = 0; r < 4; ++r) { float v = acc[r]; s[mt] += v; q[mt] += v * v; }
    }
  }
#pragma unroll
  for (int mt = 0; mt < 3; ++mt) {
    float sv = s[mt], qv = q[mt];
#pragma unroll
    for (int off = 1; off <= 8; off <<= 1) {
      sv += __shfl_xor(sv, off, 64);
      qv += __shfl_xor(qv, off, 64);
    }
    if (m == 0 && ((mt < 2) || (quad < 2))) {
      atomicAdd(&sstat[mt * 4 + quad], sv);
      atomicAdd(&sstat[10 + mt * 4 + quad], qv);
    }
  }
  __syncthreads();
  if (tid < 20) atomicAdd(&stats[(blockIdx.x & (NCOPY - 1)) * 32 + tid], sstat[tid]);
}

// ---------------- MFMA conv2 band with FUSED conv1 recompute ----------------
// Pixel->MFMA-column mapping is pooled-major: i = q*4 + corner. Maxpool is done
// in-register via shfl_xor(1/2) + packed f16 max; no LDS pool round-trip.
// NOTE: do NOT add __launch_bounds__(256,4) here — r7/r8 showed it forces scratch
// spill on this fat kernel. Do NOT fully unroll the c-loop (VGPR > 64 halves
// waves/SIMD). R=4 bands (LDS 15.6KB, NSW=2): 55% occupancy, VALU-bound at 71%.
template<int R>
__device__ __forceinline__ void band_impl(
    const int img, const int y0,
    const float* __restrict__ x, const _Float16* __restrict__ K1h,
    const _Float16* __restrict__ Wl,
    float* __restrict__ xpatch, _Float16* __restrict__ tile,
    const float* __restrict__ sc, const float* __restrict__ sh,
    float* __restrict__ sstat, _Float16* __restrict__ T0) {
  constexpr int NPIX = R * 28, NSUB = NPIX / 16, NSW = (NSUB + 3) / 4;
  constexpr int SROWS = R + 2, XR = R + 4;
  const int tid = threadIdx.x;
  const int lane = tid & 63, wv = tid >> 6;
  const int m = lane & 15, quad = lane >> 4;

  for (int i = tid; i < XR * 32; i += 256) {
    int gy = y0 - 2 + i / 32, gx = i % 32 - 2;
    xpatch[i] = (gy >= 0 && gy < 28 && gx >= 0 && gx < 28)
                    ? x[(long)img * 784 + gy * 28 + gx] : 0.f;
  }
  __syncthreads();

  // staging: conv1 via f16 MFMA -> BN1+ReLU -> f16 tile [pix][ci], packed stores
  {
    v8h a1[3];
#pragma unroll
    for (int mt = 0; mt < 3; ++mt)
      a1[mt] = *(const v8h*)(K1h + (mt * 64 + lane) * 8);
    constexpr int NPIXS = SROWS * 30;
    constexpr int NST = (NPIXS + 15) / 16;
    for (int st = wv; st < NST; st += 4) {
      const int p = st * 16 + m;
      const int pc = p < NPIXS ? p : NPIXS - 1;   // clamp tail subtile (LDS safety)
      const int iy = pc / 30, ix = pc % 30;
      v8h b;
#pragma unroll
      for (int j = 0; j < 8; ++j) {
        const int t = quad * 8 + j;
        float v = 0.f;
        if (t < 9) v = xpatch[(iy + t / 3) * 32 + ix + t % 3];
        b[j] = (_Float16)v;
      }
      const int gy = y0 + iy - 1, gx = ix - 1;
      const bool wr = p < NPIXS;
      const bool inb = wr && gy >= 0 && gy < 28 && gx >= 0 && gx < 28;
      _Float16* tb = &tile[pc * 40];
#pragma unroll
      for (int mt = 0; mt < 3; ++mt) {
        v4f a = {0.f, 0.f, 0.f, 0.f};
        a = __builtin_amdgcn_mfma_f32_16x16x32_f16(a1[mt], b, a, 0, 0, 0);
        if (((mt < 2) || (quad < 2)) && wr) {
          const int f = mt * 4 + quad;
          const float scf = sc[f], shf = sh[f];
          v4h pk;
#pragma unroll
          for (int r = 0; r < 4; ++r)
            pk[r] = inb ? (_Float16)fmaxf(0.f, fmaf(a[r], scf, shf)) : (_Float16)0.f;
          *(v4h*)(tb + mt * 16 + quad * 4) = pk;
        }
      }
    }
  }
  __syncthreads();

  // pooled-major pixel mapping: column i = q*4+corner, q = pooled pixel
  int pbase[NSW];
  bool sv[NSW];
#pragma unroll
  for (int s = 0; s < NSW; ++s) {
    int ns = wv + 4 * s;
    sv[s] = ns < NSUB;
    int i = (sv[s] ? ns : 0) * 16 + m;
    int q = i >> 2, c2 = i & 3;
    int yy = 2 * (q / 14) + (c2 >> 1), xx = 2 * (q % 14) + (c2 & 1);
    pbase[s] = (yy * 30 + xx) * 40;
  }
  v4f acc[3][NSW] = {};

  const _Float16* wlane = Wl + (quad * 16 + m) * 8;
  for (int c = 0; c < 12; ++c) {
    int g = 4 * c + quad; g = g > 44 ? 44 : g;
    int tap = g / 5, cig = g - tap * 5;
    int boff = ((tap / 3) * 30 + (tap % 3)) * 40 + cig * 8;
    v8h bfr[NSW];
#pragma unroll
    for (int s = 0; s < NSW; ++s)
      if (sv[s]) bfr[s] = *(const v8h*)&tile[pbase[s] + boff];
    v8h afr[3];
#pragma unroll
    for (int mt = 0; mt < 3; ++mt)
      afr[mt] = *(const v8h*)(wlane + (mt * 12 + c) * 512);
#pragma unroll
    for (int s = 0; s < NSW; ++s)
      if (sv[s]) {
#pragma unroll
        for (int mt = 0; mt < 3; ++mt)
          acc[mt][s] = __builtin_amdgcn_mfma_f32_16x16x32_f16(afr[mt], bfr[s],
                                                             acc[mt][s], 0, 0, 0);
      }
  }

  // full-res BN2 stats (order-invariant under pixel permutation)
#pragma unroll
  for (int mt = 0; mt < 3; ++mt) {
    float svv = 0.f, qvv = 0.f;
#pragma unroll
    for (int s = 0; s < NSW; ++s)
      if (sv[s]) {
#pragma unroll
        for (int r = 0; r < 4; ++r) { float v = acc[mt][s][r]; svv += v; qvv += v * v; }
      }
    const bool ocok = (mt < 2) || (quad < 2);
#pragma unroll
    for (int off = 1; off <= 8; off <<= 1) {
      svv += __shfl_xor(svv, off, 64);
      qvv += __shfl_xor(qvv, off, 64);
    }
    if (m == 0 && ocok) {
      atomicAdd(&sstat[mt * 4 + quad], svv);
      atomicAdd(&sstat[10 + mt * 4 + quad], qvv);
    }
  }

  // in-register 2x2 maxpool: corners live in lanes differing in m bits 0..1;
  // shfl partners share quad, so the ocok mask is shfl-safe.
#pragma unroll
  for (int s = 0; s < NSW; ++s) {
    if (!sv[s]) continue;
    const int ns = wv + 4 * s;
    const int q = ns * 4 + (m >> 2);
    const int tb4 = (img * 256 + (y0 / 2 + q / 14 + 1) * 16 + (q % 14 + 1)) * 40;
#pragma unroll
    for (int mt = 0; mt < 3; ++mt) {
      const bool ocok = (mt < 2) || (quad < 2);
      if (!ocok) continue;
      v2h w0, w1;
      w0[0] = (_Float16)acc[mt][s][0]; w0[1] = (_Float16)acc[mt][s][1];
      w1[0] = (_Float16)acc[mt][s][2]; w1[1] = (_Float16)acc[mt][s][3];
      int a0 = h2i(w0), a1 = h2i(w1);
      a0 = pmax2(a0, __shfl_xor(a0, 1, 64));
      a0 = pmax2(a0, __shfl_xor(a0, 2, 64));
      a1 = pmax2(a1, __shfl_xor(a1, 1, 64));
      a1 = pmax2(a1, __shfl_xor(a1, 2, 64));
      if ((m & 3) == 0) {
        v2h r0 = i2h(a0), r1 = i2h(a1);
        v4h o;
        o[0] = r0[0]; o[1] = r0[1]; o[2] = r1[0]; o[3] = r1[1];
        *(v4h*)(T0 + (long)tb4 + mt * 16 + quad * 4) = o;
      }
    }
  }
}

__global__ __launch_bounds__(256) void conv_band_all(
    const float* __restrict__ x, const _Float16* __restrict__ K1h,
    const _Float16* __restrict__ Wl, const float* __restrict__ pstats,
    const float* __restrict__ pgamma, const float* __restrict__ pbeta,
    _Float16* __restrict__ T0, float* __restrict__ stats) {
  __shared__ __attribute__((aligned(16))) _Float16 tile[6 * 30 * 40];
  __shared__ float xpatch[8 * 32];
  __shared__ float sc[10], sh[10], sstat[20];
  const int tid = threadIdx.x;
  if (tid < 20) sstat[tid] = 0.f;
  if (tid >= 32 && tid < 42) {
    int f = tid - 32;
    float mu = statN(pstats, f) * INV28, q = statN(pstats, 10 + f) * INV28;
    float isd = rsqrtf(q - mu * mu + EPSV);
    float s = pgamma[f] * isd;
    sc[f] = s; sh[f] = pbeta[f] - mu * s;
  }
  // (band_impl's first __syncthreads covers sc/sh + xpatch)
  const int bid = blockIdx.x;
  const int img = bid / 7, y0 = (bid % 7) * 4;
  band_impl<4>(img, y0, x, K1h, Wl, xpatch, tile, sc, sh, sstat, T0);
  __syncthreads();
  if (tid < 20) atomicAdd(&stats[(bid & (NCOPY - 1)) * 32 + tid], sstat[tid]);
}

// ---------------- tail conv layer on compact tiles (conv3..conv6) ----------------
// IN-PLACE on one buffer T: each block stages its OWN image's full tile into LDS
// (all global reads barrier-separated from the interior writeback), so no
// cross-block aliasing exists. Saves the T1 ping-pong buffer entirely.
__global__ __launch_bounds__(256) void conv_tile(
    _Float16* T, const _Float16* __restrict__ Wl,
    const float* __restrict__ pstats, const float* __restrict__ pg,
    const float* __restrict__ pb, float pinvn, float* __restrict__ stG) {
  __shared__ __attribute__((aligned(16))) _Float16 tile[256 * 40];
  __shared__ v2h scH[10], shH[10];
  __shared__ float sstat[20];
  const int tid = threadIdx.x, img = blockIdx.x;
  const int lane = tid & 63, wv = tid >> 6;
  const int m = lane & 15, quad = lane >> 4;
  if (tid < 20) sstat[tid] = 0.f;
  if (tid >= 32 && tid < 42) {
    int f = tid - 32;
    float mu = statN(pstats, f) * pinvn, q = statN(pstats, 10 + f) * pinvn;
    float isd = rsqrtf(q - mu * mu + EPSV);
    float s = pg[f] * isd;
    _Float16 sH = (_Float16)s, hH = (_Float16)(pb[f] - mu * s);
    v2h t0, t1;
    t0[0] = sH; t0[1] = sH; t1[0] = hH; t1[1] = hH;
    scH[f] = t0; shH[f] = t1;
  }
  __syncthreads();
  // staging: coalesced 16B loads, packed f16 BN+ReLU, border forced zero
  {
    const int iy = tid >> 4, ix = tid & 15;
    const bool border = (iy == 0) | (iy == 15) | (ix == 0) | (ix == 15);
    const _Float16* src = T + ((long)img * 256 + tid) * 40;
    _Float16* dst = &tile[tid * 40];
    if (!border) {
#pragma unroll
      for (int cg5 = 0; cg5 < 5; ++cg5) {
        v8h rv = *(const v8h*)(src + cg5 * 8);
        v2h* r2 = (v2h*)&rv;
        v8h pk; v2h* p2 = (v2h*)&pk;
#pragma unroll
        for (int pr = 0; pr < 4; ++pr) {
          const int f = cg5 * 2 + (pr >> 1);
          v2h t = r2[pr] * scH[f] + shH[f];
          v2h o;
          o[0] = t[0] > (_Float16)0.f ? t[0] : (_Float16)0.f;
          o[1] = t[1] > (_Float16)0.f ? t[1] : (_Float16)0.f;
          p2[pr] = o;
        }
        *(v8h*)(dst + cg5 * 8) = pk;
      }
    } else {
      v8h z;
#pragma unroll
      for (int u = 0; u < 8; ++u) z[u] = (_Float16)0.f;
#pragma unroll
      for (int cg5 = 0; cg5 < 5; ++cg5) *(v8h*)(dst + cg5 * 8) = z;
    }
  }
  __syncthreads();

  int pb3[4], n3[4];
  bool sv3[4], va3[4];
#pragma unroll
  for (int s = 0; s < 4; ++s) {
    int ns = wv + 4 * s;
    sv3[s] = ns < 13;
    int n = ns * 16 + m;
    va3[s] = sv3[s] && (n < 196);
    n = n < 196 ? n : 195;
    n3[s] = n;
    pb3[s] = ((n / 14) * 16 + (n % 14)) * 40;
  }
  const int wofs = (quad * 16 + m) * 8;
  v4f acc[3][4];
#pragma unroll
  for (int mt = 0; mt < 3; ++mt)
#pragma unroll
    for (int s = 0; s < 4; ++s) acc[mt][s] = (v4f){0.f, 0.f, 0.f, 0.f};
  for (int c = 0; c < 12; ++c) {
    int g = 4 * c + quad; g = g > 44 ? 44 : g;
    int tap = g / 5, cig = g - tap * 5;
    int boff = ((tap / 3) * 16 + (tap % 3)) * 40 + cig * 8;
    v8h bfr[4];
#pragma unroll
    for (int s = 0; s < 4; ++s)
      if (sv3[s]) bfr[s] = *(const v8h*)&tile[pb3[s] + boff];
    v8h afr[3];
#pragma unroll
    for (int mt = 0; mt < 3; ++mt)
      afr[mt] = *(const v8h*)(Wl + wofs + (mt * 12 + c) * 512);
#pragma unroll
    for (int s = 0; s < 4; ++s)
      if (sv3[s]) {
#pragma unroll
        for (int mt = 0; mt < 3; ++mt)
          acc[mt][s] = __builtin_amdgcn_mfma_f32_16x16x32_f16(afr[mt], bfr[s],
                                                             acc[mt][s], 0, 0, 0);
      }
  }

#pragma unroll
  for (int mt = 0; mt < 3; ++mt) {
    float svv = 0.f, qvv = 0.f;
#pragma unroll
    for (int s = 0; s < 4; ++s)
      if (va3[s]) {
#pragma unroll
        for (int r = 0; r < 4; ++r) { float v = acc[mt][s][r]; svv += v; qvv += v * v; }
      }
    const bool ocok = (mt < 2) || (quad < 2);
#pragma unroll
    for (int off = 1; off <= 8; off <<= 1) {
      svv += __shfl_xor(svv, off, 64);
      qvv += __shfl_xor(qvv, off, 64);
    }
    if (m == 0 && ocok) {
      atomicAdd(&sstat[mt * 4 + quad], svv);
      atomicAdd(&sstat[10 + mt * 4 + quad], qvv);
    }
  }
  __syncthreads();
  if (tid < 20) atomicAdd(&stG[(blockIdx.x & (NCOPY - 1)) * 32 + tid], sstat[tid]);

  // raw fp16 writeback IN PLACE, interior pixels, 8B packed
#pragma unroll
  for (int mt = 0; mt < 3; ++mt) {
    const bool ocok = (mt < 2) || (quad < 2);
    if (!ocok) continue;
#pragma unroll
    for (int s = 0; s < 4; ++s)
      if (va3[s]) {
        v4h pk;
#pragma unroll
        for (int r = 0; r < 4; ++r) pk[r] = (_Float16)acc[mt][s][r];
        const int n = n3[s];
        *(v4h*)(T + ((long)img * 256 + (n / 14 + 1) * 16 + (n % 14 + 1)) * 40
                + mt * 16 + quad * 4) = pk;
      }
  }
}

// ---------------- conv7 (4x4 valid, 14->11) on compact tiles ----------------
__global__ __launch_bounds__(256) void conv7_tile(
    const _Float16* __restrict__ Tin, const _Float16* __restrict__ Wl,
    const float* __restrict__ pstats, const float* __restrict__ pg,
    const float* __restrict__ pb,
    _Float16* __restrict__ T7, float* __restrict__ stG) {
  __shared__ __attribute__((aligned(16))) _Float16 tile[256 * 40];
  __shared__ v2h scH[10], shH[10];
  __shared__ float sstat[20];
  const int tid = threadIdx.x, img = blockIdx.x;
  const int lane = tid & 63, wv = tid >> 6;
  const int m = lane & 15, quad = lane >> 4;
  if (tid < 20) sstat[tid] = 0.f;
  if (tid >= 32 && tid < 42) {
    int f = tid - 32;
    float mu = statN(pstats, f) * INV14, q = statN(pstats, 10 + f) * INV14;
    float isd = rsqrtf(q - mu * mu + EPSV);
    float s = pg[f] * isd;
    _Float16 sH = (_Float16)s, hH = (_Float16)(pb[f] - mu * s);
    v2h t0, t1;
    t0[0] = sH; t0[1] = sH; t1[0] = hH; t1[1] = hH;
    scH[f] = t0; shH[f] = t1;
  }
  __syncthreads();
  {
    const int iy = tid >> 4, ix = tid & 15;
    const bool border = (iy == 0) | (iy == 15) | (ix == 0) | (ix == 15);
    const _Float16* src = Tin + ((long)img * 256 + tid) * 40;
    _Float16* dst = &tile[tid * 40];
    if (!border) {
#pragma unroll
      for (int cg5 = 0; cg5 < 5; ++cg5) {
        v8h rv = *(const v8h*)(src + cg5 * 8);
        v2h* r2 = (v2h*)&rv;
        v8h pk; v2h* p2 = (v2h*)&pk;
#pragma unroll
        for (int pr = 0; pr < 4; ++pr) {
          const int f = cg5 * 2 + (pr >> 1);
          v2h t = r2[pr] * scH[f] + shH[f];
          v2h o;
          o[0] = t[0] > (_Float16)0.f ? t[0] : (_Float16)0.f;
          o[1] = t[1] > (_Float16)0.f ? t[1] : (_Float16)0.f;
          p2[pr] = o;
        }
        *(v8h*)(dst + cg5 * 8) = pk;
      }
    } else {
      v8h z;
#pragma unroll
      for (int u = 0; u < 8; ++u) z[u] = (_Float16)0.f;
#pragma unroll
      for (int cg5 = 0; cg5 < 5; ++cg5) *(v8h*)(dst + cg5 * 8) = z;
    }
  }
  __syncthreads();

  int pb7[2], n7[2];
  bool va7[2];
#pragma unroll
  for (int s = 0; s < 2; ++s) {
    int ns = wv + 4 * s;
    int n = ns * 16 + m;
    va7[s] = n < 121;
    n = n < 121 ? n : 120;
    n7[s] = n;
    pb7[s] = ((n / 11 + 1) * 16 + (n % 11 + 1)) * 40;
  }
  const int wofs = (quad * 16 + m) * 8;
  v4f acc[3][2];
#pragma unroll
  for (int mt = 0; mt < 3; ++mt)
#pragma unroll
    for (int s = 0; s < 2; ++s) acc[mt][s] = (v4f){0.f, 0.f, 0.f, 0.f};
  for (int c = 0; c < 20; ++c) {
    int g = 4 * c + quad;
    int tap = g / 5, cig = g - tap * 5;
    int boff = ((tap >> 2) * 16 + (tap & 3)) * 40 + cig * 8;
    v8h bfr[2];
#pragma unroll
    for (int s = 0; s < 2; ++s) bfr[s] = *(const v8h*)&tile[pb7[s] + boff];
    v8h afr[3];
#pragma unroll
    for (int mt = 0; mt < 3; ++mt)
      afr[mt] = *(const v8h*)(Wl + wofs + (mt * 20 + c) * 512);
#pragma unroll
    for (int s = 0; s < 2; ++s)
#pragma unroll
      for (int mt = 0; mt < 3; ++mt)
        acc[mt][s] = __builtin_amdgcn_mfma_f32_16x16x32_f16(afr[mt], bfr[s],
                                                           acc[mt][s], 0, 0, 0);
  }

#pragma unroll
  for (int mt = 0; mt < 3; ++mt) {
    float svv = 0.f, qvv = 0.f;
#pragma unroll
    for (int s = 0; s < 2; ++s)
      if (va7[s]) {
#pragma unroll
        for (int r = 0; r < 4; ++r) { float v = acc[mt][s][r]; svv += v; qvv += v * v; }
      }
    const bool ocok = (mt < 2) || (quad < 2);
#pragma unroll
    for (int off = 1; off <= 8; off <<= 1) {
      svv += __shfl_xor(svv, off, 64);
      qvv += __shfl_xor(qvv, off, 64);
    }
    if (m == 0 && ocok) {
      atomicAdd(&sstat[mt * 4 + quad], svv);
      atomicAdd(&sstat[10 + mt * 4 + quad], qvv);
    }
  }
  __syncthreads();
  if (tid < 20) atomicAdd(&stG[(blockIdx.x & (NCOPY - 1)) * 32 + tid], sstat[tid]);

#pragma unroll
  for (int mt = 0; mt < 3; ++mt) {
    const bool ocok = (mt < 2) || (quad < 2);
    if (!ocok) continue;
#pragma unroll
    for (int s = 0; s < 2; ++s)
      if (va7[s]) {
        v4h pk;
#pragma unroll
        for (int r = 0; r < 4; ++r) pk[r] = (_Float16)acc[mt][s][r];
        *(v4h*)(T7 + ((long)img * 121 + n7[s]) * 40 + mt * 16 + quad * 4) = pk;
      }
  }
}

// ---------------- head: BN7+ReLU -> orientation max -> FC ----------------
__global__ __launch_bounds__(256) void head_kernel(
    const _Float16* __restrict__ T7, const float* __restrict__ stats7,
    const float* __restrict__ gs, const float* __restrict__ bs,
    const float* __restrict__ wfc, const float* __restrict__ bfc,
    float* __restrict__ out) {
  __shared__ float sc[10], sh[10];
  __shared__ float mbuf[1210];
  __shared__ float red[40];
  const int tid = threadIdx.x, img = blockIdx.x;
  if (tid < 10) {
    float mu = statN(stats7, tid) * INV11, q = statN(stats7, 10 + tid) * INV11;
    float isd = rsqrtf(q - mu * mu + EPSV);
    float s = gs[tid] * isd;
    sc[tid] = s;
    sh[tid] = bs[tid] - mu * s;
  }
  __syncthreads();
  for (int p = tid; p < 121; p += 256) {
    const _Float16* rp = T7 + ((long)img * 121 + p) * 40;
#pragma unroll
    for (int cg5 = 0; cg5 < 5; ++cg5) {
      v8h v = *(const v8h*)(rp + cg5 * 8);
#pragma unroll
      for (int fh = 0; fh < 2; ++fh) {
        const int f = cg5 * 2 + fh;
        float mx = fmaf((float)v[fh * 4], sc[f], sh[f]);
#pragma unroll
        for (int r = 1; r < 4; ++r)
          mx = fmaxf(mx, fmaf((float)v[fh * 4 + r], sc[f], sh[f]));
        mbuf[f * 121 + p] = fmaxf(0.f, mx);
      }
    }
  }
  __syncthreads();
  const int wv = tid >> 6;
  for (int k = 0; k < 10; ++k) {
    float p = 0.f;
    for (int j = tid; j < 1210; j += 256) p = fmaf(mbuf[j], wfc[k * 1210 + j], p);
#pragma unroll
    for (int off = 32; off > 0; off >>= 1) p += __shfl_xor(p, off, 64);
    if ((tid & 63) == 0) red[k * 4 + wv] = p;
  }
  __syncthreads();
  if (tid < 10)
    out[img * 10 + tid] = bfc[tid] + red[tid * 4] + red[tid * 4 + 1] +
                          red[tid * 4 + 2] + red[tid * 4 + 3];
}

extern "C" void kernel_launch(void* const* d_in, const int* in_sizes, int n_in,
                              void* d_out, int out_size, void* d_ws, size_t ws_size,
                              hipStream_t stream) {
  const float* x   = (const float*)d_in[0];
  const float* w1  = (const float*)d_in[1];
  const float* w2  = (const float*)d_in[2];
  const float* w3  = (const float*)d_in[3];
  const float* w4  = (const float*)d_in[4];
  const float* w5  = (const float*)d_in[5];
  const float* w6  = (const float*)d_in[6];
  const float* w7  = (const float*)d_in[7];
  const float* g1  = (const float*)d_in[8];
  const float* b1  = (const float*)d_in[9];
  const float* g2  = (const float*)d_in[10];
  const float* b2  = (const float*)d_in[11];
  const float* gs  = (const float*)d_in[12];
  const float* bs  = (const float*)d_in[13];
  const float* wfc = (const float*)d_in[14];
  const float* bfc = (const float*)d_in[15];

  float* ws = (float*)d_ws;
  // Workspace (floats), ~31.2 MB total (T1 removed; tail is in-place on T0):
  float* stats  = ws;                          // 7 layers x NCOPY(64) x 32 = 14336
  _Float16* K1h = (_Float16*)(ws + 14336);     // 1536 fp16 (conv1 MFMA A-table)
  _Float16* Wh  = (_Float16*)(ws + 15104);     // 122,880 fp16 -> ends 76544
  _Float16* T0  = (_Float16*)(ws + 76544);     // tile [1024][256][40] fp16 -> ends 5319424
  _Float16* T7  = (_Float16*)(ws + 5319424L);  // conv7 raw [1024][121][40] fp16

  prep_kernel<<<543, 256, 0, stream>>>(w1, w2, w3, w4, w5, w6, w7, K1h, Wh, stats);
  conv1_stats<<<1024, 256, 0, stream>>>(x, K1h, stats);
  // conv2 (conv1 fused in staging): all R=4 bands, in-register pooled raw -> T0
  conv_band_all<<<7168, 256, 0, stream>>>(x, K1h, Wh, stats, g1, b1, T0,
                                          stats + LSTRIDE);
  // conv3..conv6 in place on T0
  conv_tile<<<1024, 256, 0, stream>>>(T0, Wh + 18432, stats + LSTRIDE, g2, b2, INV28,
                                      stats + 2 * LSTRIDE);
  conv_tile<<<1024, 256, 0, stream>>>(T0, Wh + 36864, stats + 2 * LSTRIDE, gs, bs, INV14,
                                      stats + 3 * LSTRIDE);
  conv_tile<<<1024, 256, 0, stream>>>(T0, Wh + 55296, stats + 3 * LSTRIDE, gs, bs, INV14,
                                      stats + 4 * LSTRIDE);
  conv_tile<<<1024, 256, 0, stream>>>(T0, Wh + 73728, stats + 4 * LSTRIDE, gs, bs, INV14,
                                      stats + 5 * LSTRIDE);
  // conv7
  conv7_tile<<<1024, 256, 0, stream>>>(T0, Wh + 92160, stats + 5 * LSTRIDE, gs, bs,
                                       T7, stats + 6 * LSTRIDE);
  // head
  head_kernel<<<1024, 256, 0, stream>>>(T7, stats + 6 * LSTRIDE, gs, bs, wfc, bfc,
                                        (float*)d_out);
}

// Round 10
// 270.265 us; speedup vs baseline: 1.1529x; 1.1529x over previous
//
#include <hip/hip_runtime.h>

#define EPSV 1e-5f
#define INV28 (1.f / 3211264.f)
#define INV14 (1.f / 802816.f)
#define INV11 (1.f / 495616.f)
// BN-stats shadow copies: 8 (R7 best-known). R8/R9 lesson: NCOPY=64 never paid —
// write-side atomic contention was NOT the tail cost (dispatch boundaries are,
// ~12-15us each, from R6's fused-tail 33us-compute datum); and the 64-wide
// reader either stalls (rolled atomics, R8) or blows VGPR 40->52 and occupancy
// 55->38% (full unroll, R9). 8 plain unrolled loads is cheap on both axes.
#define NCOPY 8
#define LSTRIDE 256   // floats per layer stats region (NCOPY*32)

typedef _Float16 v8h __attribute__((ext_vector_type(8)));
typedef _Float16 v4h __attribute__((ext_vector_type(4)));
typedef _Float16 v2h __attribute__((ext_vector_type(2)));
typedef float v4f __attribute__((ext_vector_type(4)));

__device__ __forceinline__ int h2i(v2h v) { union { v2h h; int i; } u; u.h = v; return u.i; }
__device__ __forceinline__ v2h i2h(int i) { union { v2h h; int i; } u; u.i = i; return u.h; }
__device__ __forceinline__ int pmax2(int a, int b) {
  v2h x = i2h(a), y = i2h(b), r;
  r[0] = x[0] > y[0] ? x[0] : y[0];
  r[1] = x[1] > y[1] ? x[1] : y[1];
  return h2i(r);
}

// rot90 applied r times CCW (np.rot90 semantics): out[dy][dx] = m[sy][sx]
__device__ __forceinline__ int rotsrc(int r, int dy, int dx, int K) {
  int sy, sx;
  if (r == 0)      { sy = dy;       sx = dx; }
  else if (r == 1) { sy = dx;       sx = K - 1 - dy; }
  else if (r == 2) { sy = K - 1 - dy; sx = K - 1 - dx; }
  else             { sy = K - 1 - dx; sx = dy; }
  return sy * K + sx;
}

// P4 weight expansion: value for output channel oc, k-group g, index j.
// g = (tap, ci-group-of-8): tap = g/5, ci = (g%5)*8+j.
__device__ __forceinline__ float gw_val(const float* __restrict__ w, int oc, int g,
                                        int j, int KS) {
  int tap = g / 5, cig = g % 5, ci = cig * 8 + j;
  int co = oc >> 2, r = oc & 3, cin = ci >> 2, s = ci & 3;
  int srel = (s - r) & 3;
  return w[((co * 10 + cin) * 4 + srel) * (KS * KS) + rotsrc(r, tap / KS, tap % KS, KS)];
}

// conv1 lifted-weight A-fragment element for a given lane/mt/j (K=32 zero-pad).
__device__ __forceinline__ _Float16 k1_val(const float* __restrict__ w1,
                                           int lane, int mt, int j) {
  const int m = lane & 15, quad = lane >> 4;
  const int k = quad * 8 + j, oc = mt * 16 + m;
  float val = 0.f;
  if (k < 9 && oc < 40) {
    int c = oc >> 2, r = oc & 3;
    val = w1[c * 9 + rotsrc(r, k / 3, k % 3, 3)];
  }
  return (_Float16)val;
}

// stats read: written by a PREVIOUS dispatch (ordering via launch boundary),
// so plain loads suffice. 8 unrolled loads: one round trip, ~4 live VGPRs.
__device__ __forceinline__ float statN(const float* __restrict__ p, int i) {
  float v = 0.f;
#pragma unroll
  for (int c = 0; c < NCOPY; ++c) v += p[c * 32 + i];
  return v;
}

// ---------------- merged: weight tables + conv1 BN-stats ----------------
// Stats zeroing is done by a hipMemsetAsync node before this dispatch (R10:
// removes the prep->conv1_stats boundary; the conv1-stats blocks self-compute
// their tiny A-fragments from w1 so they need no table dependency).
// NOTE (R4-R6 lesson): software grid barriers cost ~37us/phase on this chip
// regardless of contention structure; kernel launch boundaries (~12us) are the
// cheaper grid-wide ordering -> per-BN-layer split stays.
__global__ __launch_bounds__(256) void prep_stats(
    const float* __restrict__ x,
    const float* __restrict__ w1, const float* __restrict__ w2,
    const float* __restrict__ w3, const float* __restrict__ w4,
    const float* __restrict__ w5, const float* __restrict__ w6,
    const float* __restrict__ w7,
    _Float16* __restrict__ K1h, _Float16* __restrict__ Wh,
    float* __restrict__ stats) {
  __shared__ float ximg[900];
  __shared__ float sstat[20];
  const int tid = threadIdx.x;
  if (blockIdx.x < 486) {   // table role: 486*256 = 124416 table entries exactly
    int idx = blockIdx.x * blockDim.x + tid;
    if (idx < 1536) { // conv1 lifted weights in MFMA A-fragment layout
      int mt = idx >> 9, l = (idx >> 3) & 63, j = idx & 7;
      K1h[idx] = k1_val(w1, l, mt, j);
      return;
    }
    idx -= 1536;
    if (idx < 92160) { // conv2..conv6: 5 layers x [3][12][4][16][8]
      int l = idx / 18432, r0 = idx % 18432;
      const float* w = (l == 0) ? w2 : (l == 1) ? w3 : (l == 2) ? w4
                                                : (l == 3) ? w5 : w6;
      int mt = r0 / 6144, r1 = r0 % 6144;
      int c = r1 / 512, r2 = r1 % 512;
      int q = r2 / 128, r3 = r2 % 128;
      int ocl = r3 / 8, j = r3 % 8;
      int oc = mt * 16 + ocl, g = c * 4 + q;
      float val = 0.f;
      if (oc < 40 && g < 45) val = gw_val(w, oc, g, j, 3);
      Wh[idx] = (_Float16)val;
      return;
    }
    idx -= 92160;
    { // conv7: [3][20][4][16][8], 30720 entries
      int mt = idx / 10240, r1 = idx % 10240;
      int c = r1 / 512, r2 = r1 % 512;
      int q = r2 / 128, r3 = r2 % 128;
      int ocl = r3 / 8, j = r3 % 8;
      int oc = mt * 16 + ocl, g = c * 4 + q;
      float val = 0.f;
      if (oc < 40) val = gw_val(w7, oc, g, j, 4);
      Wh[92160 + idx] = (_Float16)val;
    }
    return;
  }

  // conv1-stats role: MFMA conv1, no activation materialized
  const int img = blockIdx.x - 486;
  if (tid < 20) sstat[tid] = 0.f;
  for (int i = tid; i < 900; i += 256) {
    int gy = i / 30 - 1, gx = i % 30 - 1;
    ximg[i] = (gy >= 0 && gy < 28 && gx >= 0 && gx < 28)
                  ? x[img * 784 + gy * 28 + gx] : 0.f;
  }
  __syncthreads();
  const int lane = tid & 63, wv = tid >> 6;
  const int m = lane & 15, quad = lane >> 4;
  v8h a1[3];
#pragma unroll
  for (int mt = 0; mt < 3; ++mt)
#pragma unroll
    for (int j = 0; j < 8; ++j) a1[mt][j] = k1_val(w1, lane, mt, j);
  float s[3] = {0.f, 0.f, 0.f}, q[3] = {0.f, 0.f, 0.f};
  for (int st = wv; st < 49; st += 4) {   // 784 = 49 x 16 pixels, exact
    const int p = st * 16 + m;
    const int y = p / 28, xx = p % 28;
    v8h b;
#pragma unroll
    for (int j = 0; j < 8; ++j) {
      const int t = quad * 8 + j;
      float v = 0.f;
      if (t < 9) v = ximg[(y + t / 3) * 30 + xx + t % 3];
      b[j] = (_Float16)v;
    }
#pragma unroll
    for (int mt = 0; mt < 3; ++mt) {
      v4f acc = {0.f, 0.f, 0.f, 0.f};
      acc = __builtin_amdgcn_mfma_f32_16x16x32_f16(a1[mt], b, acc, 0, 0, 0);
#pragma unroll
      for (int r = 0; r < 4; ++r) { float v = acc[r]; s[mt] += v; q[mt] += v * v; }
    }
  }
#pragma unroll
  for (int mt = 0; mt < 3; ++mt) {
    float sv = s[mt], qv = q[mt];
#pragma unroll
    for (int off = 1; off <= 8; off <<= 1) {
      sv += __shfl_xor(sv, off, 64);
      qv += __shfl_xor(qv, off, 64);
    }
    if (m == 0 && ((mt < 2) || (quad < 2))) {
      atomicAdd(&sstat[mt * 4 + quad], sv);
      atomicAdd(&sstat[10 + mt * 4 + quad], qv);
    }
  }
  __syncthreads();
  if (tid < 20) atomicAdd(&stats[(img & (NCOPY - 1)) * 32 + tid], sstat[tid]);
}

// ---------------- MFMA conv2 band with FUSED conv1 recompute ----------------
// Pixel->MFMA-column mapping is pooled-major: i = q*4 + corner. Maxpool is done
// in-register via shfl_xor(1/2) + packed f16 max; no LDS pool round-trip.
// NOTE: do NOT add __launch_bounds__(256,4) here — forces scratch spill. Do NOT
// fully unroll the c-loop (VGPR > 64 halves waves/SIMD). Do NOT widen statN
// reads (R9: VGPR 40->52, occ 55->38%). R=4 bands (LDS 15.6KB, NSW=2).
template<int R>
__device__ __forceinline__ void band_impl(
    const int img, const int y0,
    const float* __restrict__ x, const _Float16* __restrict__ K1h,
    const _Float16* __restrict__ Wl,
    float* __restrict__ xpatch, _Float16* __restrict__ tile,
    const float* __restrict__ sc, const float* __restrict__ sh,
    float* __restrict__ sstat, _Float16* __restrict__ T0) {
  constexpr int NPIX = R * 28, NSUB = NPIX / 16, NSW = (NSUB + 3) / 4;
  constexpr int SROWS = R + 2, XR = R + 4;
  const int tid = threadIdx.x;
  const int lane = tid & 63, wv = tid >> 6;
  const int m = lane & 15, quad = lane >> 4;

  for (int i = tid; i < XR * 32; i += 256) {
    int gy = y0 - 2 + i / 32, gx = i % 32 - 2;
    xpatch[i] = (gy >= 0 && gy < 28 && gx >= 0 && gx < 28)
                    ? x[(long)img * 784 + gy * 28 + gx] : 0.f;
  }
  __syncthreads();

  // staging: conv1 via f16 MFMA -> BN1+ReLU -> f16 tile [pix][ci], packed stores
  {
    v8h a1[3];
#pragma unroll
    for (int mt = 0; mt < 3; ++mt)
      a1[mt] = *(const v8h*)(K1h + (mt * 64 + lane) * 8);
    constexpr int NPIXS = SROWS * 30;
    constexpr int NST = (NPIXS + 15) / 16;
    for (int st = wv; st < NST; st += 4) {
      const int p = st * 16 + m;
      const int pc = p < NPIXS ? p : NPIXS - 1;   // clamp tail subtile (LDS safety)
      const int iy = pc / 30, ix = pc % 30;
      v8h b;
#pragma unroll
      for (int j = 0; j < 8; ++j) {
        const int t = quad * 8 + j;
        float v = 0.f;
        if (t < 9) v = xpatch[(iy + t / 3) * 32 + ix + t % 3];
        b[j] = (_Float16)v;
      }
      const int gy = y0 + iy - 1, gx = ix - 1;
      const bool wr = p < NPIXS;
      const bool inb = wr && gy >= 0 && gy < 28 && gx >= 0 && gx < 28;
      _Float16* tb = &tile[pc * 40];
#pragma unroll
      for (int mt = 0; mt < 3; ++mt) {
        v4f a = {0.f, 0.f, 0.f, 0.f};
        a = __builtin_amdgcn_mfma_f32_16x16x32_f16(a1[mt], b, a, 0, 0, 0);
        if (((mt < 2) || (quad < 2)) && wr) {
          const int f = mt * 4 + quad;
          const float scf = sc[f], shf = sh[f];
          v4h pk;
#pragma unroll
          for (int r = 0; r < 4; ++r)
            pk[r] = inb ? (_Float16)fmaxf(0.f, fmaf(a[r], scf, shf)) : (_Float16)0.f;
          *(v4h*)(tb + mt * 16 + quad * 4) = pk;
        }
      }
    }
  }
  __syncthreads();

  // pooled-major pixel mapping: column i = q*4+corner, q = pooled pixel
  int pbase[NSW];
  bool sv[NSW];
#pragma unroll
  for (int s = 0; s < NSW; ++s) {
    int ns = wv + 4 * s;
    sv[s] = ns < NSUB;
    int i = (sv[s] ? ns : 0) * 16 + m;
    int q = i >> 2, c2 = i & 3;
    int yy = 2 * (q / 14) + (c2 >> 1), xx = 2 * (q % 14) + (c2 & 1);
    pbase[s] = (yy * 30 + xx) * 40;
  }
  v4f acc[3][NSW] = {};

  const _Float16* wlane = Wl + (quad * 16 + m) * 8;
  for (int c = 0; c < 12; ++c) {
    int g = 4 * c + quad; g = g > 44 ? 44 : g;
    int tap = g / 5, cig = g - tap * 5;
    int boff = ((tap / 3) * 30 + (tap % 3)) * 40 + cig * 8;
    v8h bfr[NSW];
#pragma unroll
    for (int s = 0; s < NSW; ++s)
      if (sv[s]) bfr[s] = *(const v8h*)&tile[pbase[s] + boff];
    v8h afr[3];
#pragma unroll
    for (int mt = 0; mt < 3; ++mt)
      afr[mt] = *(const v8h*)(wlane + (mt * 12 + c) * 512);
#pragma unroll
    for (int s = 0; s < NSW; ++s)
      if (sv[s]) {
#pragma unroll
        for (int mt = 0; mt < 3; ++mt)
          acc[mt][s] = __builtin_amdgcn_mfma_f32_16x16x32_f16(afr[mt], bfr[s],
                                                             acc[mt][s], 0, 0, 0);
      }
  }

  // full-res BN2 stats (order-invariant under pixel permutation)
#pragma unroll
  for (int mt = 0; mt < 3; ++mt) {
    float svv = 0.f, qvv = 0.f;
#pragma unroll
    for (int s = 0; s < NSW; ++s)
      if (sv[s]) {
#pragma unroll
        for (int r = 0; r < 4; ++r) { float v = acc[mt][s][r]; svv += v; qvv += v * v; }
      }
    const bool ocok = (mt < 2) || (quad < 2);
#pragma unroll
    for (int off = 1; off <= 8; off <<= 1) {
      svv += __shfl_xor(svv, off, 64);
      qvv += __shfl_xor(qvv, off, 64);
    }
    if (m == 0 && ocok) {
      atomicAdd(&sstat[mt * 4 + quad], svv);
      atomicAdd(&sstat[10 + mt * 4 + quad], qvv);
    }
  }

  // in-register 2x2 maxpool: corners live in lanes differing in m bits 0..1;
  // shfl partners share quad, so the ocok mask is shfl-safe.
#pragma unroll
  for (int s = 0; s < NSW; ++s) {
    if (!sv[s]) continue;
    const int ns = wv + 4 * s;
    const int q = ns * 4 + (m >> 2);
    const int tb4 = (img * 256 + (y0 / 2 + q / 14 + 1) * 16 + (q % 14 + 1)) * 40;
#pragma unroll
    for (int mt = 0; mt < 3; ++mt) {
      const bool ocok = (mt < 2) || (quad < 2);
      if (!ocok) continue;
      v2h w0, w1;
      w0[0] = (_Float16)acc[mt][s][0]; w0[1] = (_Float16)acc[mt][s][1];
      w1[0] = (_Float16)acc[mt][s][2]; w1[1] = (_Float16)acc[mt][s][3];
      int a0 = h2i(w0), a1 = h2i(w1);
      a0 = pmax2(a0, __shfl_xor(a0, 1, 64));
      a0 = pmax2(a0, __shfl_xor(a0, 2, 64));
      a1 = pmax2(a1, __shfl_xor(a1, 1, 64));
      a1 = pmax2(a1, __shfl_xor(a1, 2, 64));
      if ((m & 3) == 0) {
        v2h r0 = i2h(a0), r1 = i2h(a1);
        v4h o;
        o[0] = r0[0]; o[1] = r0[1]; o[2] = r1[0]; o[3] = r1[1];
        *(v4h*)(T0 + (long)tb4 + mt * 16 + quad * 4) = o;
      }
    }
  }
}

__global__ __launch_bounds__(256) void conv_band_all(
    const float* __restrict__ x, const _Float16* __restrict__ K1h,
    const _Float16* __restrict__ Wl, const float* __restrict__ pstats,
    const float* __restrict__ pgamma, const float* __restrict__ pbeta,
    _Float16* __restrict__ T0, float* __restrict__ stats) {
  __shared__ __attribute__((aligned(16))) _Float16 tile[6 * 30 * 40];
  __shared__ float xpatch[8 * 32];
  __shared__ float sc[10], sh[10], sstat[20];
  const int tid = threadIdx.x;
  if (tid < 20) sstat[tid] = 0.f;
  if (tid >= 32 && tid < 42) {
    int f = tid - 32;
    float mu = statN(pstats, f) * INV28, q = statN(pstats, 10 + f) * INV28;
    float isd = rsqrtf(q - mu * mu + EPSV);
    float s = pgamma[f] * isd;
    sc[f] = s; sh[f] = pbeta[f] - mu * s;
  }
  // (band_impl's first __syncthreads covers sc/sh + xpatch)
  const int bid = blockIdx.x;
  const int img = bid / 7, y0 = (bid % 7) * 4;
  band_impl<4>(img, y0, x, K1h, Wl, xpatch, tile, sc, sh, sstat, T0);
  __syncthreads();
  if (tid < 20) atomicAdd(&stats[(bid & (NCOPY - 1)) * 32 + tid], sstat[tid]);
}

// ---------------- tail conv layer on compact tiles (conv3..conv6) ----------------
// IN-PLACE on one buffer T: each block stages its OWN image's full tile into LDS
// (all global reads barrier-separated from the interior writeback), so no
// cross-block aliasing exists.
__global__ __launch_bounds__(256) void conv_tile(
    _Float16* T, const _Float16* __restrict__ Wl,
    const float* __restrict__ pstats, const float* __restrict__ pg,
    const float* __restrict__ pb, float pinvn, float* __restrict__ stG) {
  __shared__ __attribute__((aligned(16))) _Float16 tile[256 * 40];
  __shared__ v2h scH[10], shH[10];
  __shared__ float sstat[20];
  const int tid = threadIdx.x, img = blockIdx.x;
  const int lane = tid & 63, wv = tid >> 6;
  const int m = lane & 15, quad = lane >> 4;
  if (tid < 20) sstat[tid] = 0.f;
  if (tid >= 32 && tid < 42) {
    int f = tid - 32;
    float mu = statN(pstats, f) * pinvn, q = statN(pstats, 10 + f) * pinvn;
    float isd = rsqrtf(q - mu * mu + EPSV);
    float s = pg[f] * isd;
    _Float16 sH = (_Float16)s, hH = (_Float16)(pb[f] - mu * s);
    v2h t0, t1;
    t0[0] = sH; t0[1] = sH; t1[0] = hH; t1[1] = hH;
    scH[f] = t0; shH[f] = t1;
  }
  __syncthreads();
  // staging: coalesced 16B loads, packed f16 BN+ReLU, border forced zero
  {
    const int iy = tid >> 4, ix = tid & 15;
    const bool border = (iy == 0) | (iy == 15) | (ix == 0) | (ix == 15);
    const _Float16* src = T + ((long)img * 256 + tid) * 40;
    _Float16* dst = &tile[tid * 40];
    if (!border) {
#pragma unroll
      for (int cg5 = 0; cg5 < 5; ++cg5) {
        v8h rv = *(const v8h*)(src + cg5 * 8);
        v2h* r2 = (v2h*)&rv;
        v8h pk; v2h* p2 = (v2h*)&pk;
#pragma unroll
        for (int pr = 0; pr < 4; ++pr) {
          const int f = cg5 * 2 + (pr >> 1);
          v2h t = r2[pr] * scH[f] + shH[f];
          v2h o;
          o[0] = t[0] > (_Float16)0.f ? t[0] : (_Float16)0.f;
          o[1] = t[1] > (_Float16)0.f ? t[1] : (_Float16)0.f;
          p2[pr] = o;
        }
        *(v8h*)(dst + cg5 * 8) = pk;
      }
    } else {
      v8h z;
#pragma unroll
      for (int u = 0; u < 8; ++u) z[u] = (_Float16)0.f;
#pragma unroll
      for (int cg5 = 0; cg5 < 5; ++cg5) *(v8h*)(dst + cg5 * 8) = z;
    }
  }
  __syncthreads();

  int pb3[4], n3[4];
  bool sv3[4], va3[4];
#pragma unroll
  for (int s = 0; s < 4; ++s) {
    int ns = wv + 4 * s;
    sv3[s] = ns < 13;
    int n = ns * 16 + m;
    va3[s] = sv3[s] && (n < 196);
    n = n < 196 ? n : 195;
    n3[s] = n;
    pb3[s] = ((n / 14) * 16 + (n % 14)) * 40;
  }
  const int wofs = (quad * 16 + m) * 8;
  v4f acc[3][4];
#pragma unroll
  for (int mt = 0; mt < 3; ++mt)
#pragma unroll
    for (int s = 0; s < 4; ++s) acc[mt][s] = (v4f){0.f, 0.f, 0.f, 0.f};
  for (int c = 0; c < 12; ++c) {
    int g = 4 * c + quad; g = g > 44 ? 44 : g;
    int tap = g / 5, cig = g - tap * 5;
    int boff = ((tap / 3) * 16 + (tap % 3)) * 40 + cig * 8;
    v8h bfr[4];
#pragma unroll
    for (int s = 0; s < 4; ++s)
      if (sv3[s]) bfr[s] = *(const v8h*)&tile[pb3[s] + boff];
    v8h afr[3];
#pragma unroll
    for (int mt = 0; mt < 3; ++mt)
      afr[mt] = *(const v8h*)(Wl + wofs + (mt * 12 + c) * 512);
#pragma unroll
    for (int s = 0; s < 4; ++s)
      if (sv3[s]) {
#pragma unroll
        for (int mt = 0; mt < 3; ++mt)
          acc[mt][s] = __builtin_amdgcn_mfma_f32_16x16x32_f16(afr[mt], bfr[s],
                                                             acc[mt][s], 0, 0, 0);
      }
  }

#pragma unroll
  for (int mt = 0; mt < 3; ++mt) {
    float svv = 0.f, qvv = 0.f;
#pragma unroll
    for (int s = 0; s < 4; ++s)
      if (va3[s]) {
#pragma unroll
        for (int r = 0; r < 4; ++r) { float v = acc[mt][s][r]; svv += v; qvv += v * v; }
      }
    const bool ocok = (mt < 2) || (quad < 2);
#pragma unroll
    for (int off = 1; off <= 8; off <<= 1) {
      svv += __shfl_xor(svv, off, 64);
      qvv += __shfl_xor(qvv, off, 64);
    }
    if (m == 0 && ocok) {
      atomicAdd(&sstat[mt * 4 + quad], svv);
      atomicAdd(&sstat[10 + mt * 4 + quad], qvv);
    }
  }
  __syncthreads();
  if (tid < 20) atomicAdd(&stG[(blockIdx.x & (NCOPY - 1)) * 32 + tid], sstat[tid]);

  // raw fp16 writeback IN PLACE, interior pixels, 8B packed
#pragma unroll
  for (int mt = 0; mt < 3; ++mt) {
    const bool ocok = (mt < 2) || (quad < 2);
    if (!ocok) continue;
#pragma unroll
    for (int s = 0; s < 4; ++s)
      if (va3[s]) {
        v4h pk;
#pragma unroll
        for (int r = 0; r < 4; ++r) pk[r] = (_Float16)acc[mt][s][r];
        const int n = n3[s];
        *(v4h*)(T + ((long)img * 256 + (n / 14 + 1) * 16 + (n % 14 + 1)) * 40
                + mt * 16 + quad * 4) = pk;
      }
  }
}

// ---------------- conv7 (4x4 valid, 14->11) on compact tiles ----------------
__global__ __launch_bounds__(256) void conv7_tile(
    const _Float16* __restrict__ Tin, const _Float16* __restrict__ Wl,
    const float* __restrict__ pstats, const float* __restrict__ pg,
    const float* __restrict__ pb,
    _Float16* __restrict__ T7, float* __restrict__ stG) {
  __shared__ __attribute__((aligned(16))) _Float16 tile[256 * 40];
  __shared__ v2h scH[10], shH[10];
  __shared__ float sstat[20];
  const int tid = threadIdx.x, img = blockIdx.x;
  const int lane = tid & 63, wv = tid >> 6;
  const int m = lane & 15, quad = lane >> 4;
  if (tid < 20) sstat[tid] = 0.f;
  if (tid >= 32 && tid < 42) {
    int f = tid - 32;
    float mu = statN(pstats, f) * INV14, q = statN(pstats, 10 + f) * INV14;
    float isd = rsqrtf(q - mu * mu + EPSV);
    float s = pg[f] * isd;
    _Float16 sH = (_Float16)s, hH = (_Float16)(pb[f] - mu * s);
    v2h t0, t1;
    t0[0] = sH; t0[1] = sH; t1[0] = hH; t1[1] = hH;
    scH[f] = t0; shH[f] = t1;
  }
  __syncthreads();
  {
    const int iy = tid >> 4, ix = tid & 15;
    const bool border = (iy == 0) | (iy == 15) | (ix == 0) | (ix == 15);
    const _Float16* src = Tin + ((long)img * 256 + tid) * 40;
    _Float16* dst = &tile[tid * 40];
    if (!border) {
#pragma unroll
      for (int cg5 = 0; cg5 < 5; ++cg5) {
        v8h rv = *(const v8h*)(src + cg5 * 8);
        v2h* r2 = (v2h*)&rv;
        v8h pk; v2h* p2 = (v2h*)&pk;
#pragma unroll
        for (int pr = 0; pr < 4; ++pr) {
          const int f = cg5 * 2 + (pr >> 1);
          v2h t = r2[pr] * scH[f] + shH[f];
          v2h o;
          o[0] = t[0] > (_Float16)0.f ? t[0] : (_Float16)0.f;
          o[1] = t[1] > (_Float16)0.f ? t[1] : (_Float16)0.f;
          p2[pr] = o;
        }
        *(v8h*)(dst + cg5 * 8) = pk;
      }
    } else {
      v8h z;
#pragma unroll
      for (int u = 0; u < 8; ++u) z[u] = (_Float16)0.f;
#pragma unroll
      for (int cg5 = 0; cg5 < 5; ++cg5) *(v8h*)(dst + cg5 * 8) = z;
    }
  }
  __syncthreads();

  int pb7[2], n7[2];
  bool va7[2];
#pragma unroll
  for (int s = 0; s < 2; ++s) {
    int ns = wv + 4 * s;
    int n = ns * 16 + m;
    va7[s] = n < 121;
    n = n < 121 ? n : 120;
    n7[s] = n;
    pb7[s] = ((n / 11 + 1) * 16 + (n % 11 + 1)) * 40;
  }
  const int wofs = (quad * 16 + m) * 8;
  v4f acc[3][2];
#pragma unroll
  for (int mt = 0; mt < 3; ++mt)
#pragma unroll
    for (int s = 0; s < 2; ++s) acc[mt][s] = (v4f){0.f, 0.f, 0.f, 0.f};
  for (int c = 0; c < 20; ++c) {
    int g = 4 * c + quad;
    int tap = g / 5, cig = g - tap * 5;
    int boff = ((tap >> 2) * 16 + (tap & 3)) * 40 + cig * 8;
    v8h bfr[2];
#pragma unroll
    for (int s = 0; s < 2; ++s) bfr[s] = *(const v8h*)&tile[pb7[s] + boff];
    v8h afr[3];
#pragma unroll
    for (int mt = 0; mt < 3; ++mt)
      afr[mt] = *(const v8h*)(Wl + wofs + (mt * 20 + c) * 512);
#pragma unroll
    for (int s = 0; s < 2; ++s)
#pragma unroll
      for (int mt = 0; mt < 3; ++mt)
        acc[mt][s] = __builtin_amdgcn_mfma_f32_16x16x32_f16(afr[mt], bfr[s],
                                                           acc[mt][s], 0, 0, 0);
  }

#pragma unroll
  for (int mt = 0; mt < 3; ++mt) {
    float svv = 0.f, qvv = 0.f;
#pragma unroll
    for (int s = 0; s < 2; ++s)
      if (va7[s]) {
#pragma unroll
        for (int r = 0; r < 4; ++r) { float v = acc[mt][s][r]; svv += v; qvv += v * v; }
      }
    const bool ocok = (mt < 2) || (quad < 2);
#pragma unroll
    for (int off = 1; off <= 8; off <<= 1) {
      svv += __shfl_xor(svv, off, 64);
      qvv += __shfl_xor(qvv, off, 64);
    }
    if (m == 0 && ocok) {
      atomicAdd(&sstat[mt * 4 + quad], svv);
      atomicAdd(&sstat[10 + mt * 4 + quad], qvv);
    }
  }
  __syncthreads();
  if (tid < 20) atomicAdd(&stG[(blockIdx.x & (NCOPY - 1)) * 32 + tid], sstat[tid]);

#pragma unroll
  for (int mt = 0; mt < 3; ++mt) {
    const bool ocok = (mt < 2) || (quad < 2);
    if (!ocok) continue;
#pragma unroll
    for (int s = 0; s < 2; ++s)
      if (va7[s]) {
        v4h pk;
#pragma unroll
        for (int r = 0; r < 4; ++r) pk[r] = (_Float16)acc[mt][s][r];
        *(v4h*)(T7 + ((long)img * 121 + n7[s]) * 40 + mt * 16 + quad * 4) = pk;
      }
  }
}

// ---------------- head: BN7+ReLU -> orientation max -> FC ----------------
__global__ __launch_bounds__(256) void head_kernel(
    const _Float16* __restrict__ T7, const float* __restrict__ stats7,
    const float* __restrict__ gs, const float* __restrict__ bs,
    const float* __restrict__ wfc, const float* __restrict__ bfc,
    float* __restrict__ out) {
  __shared__ float sc[10], sh[10];
  __shared__ float mbuf[1210];
  __shared__ float red[40];
  const int tid = threadIdx.x, img = blockIdx.x;
  if (tid < 10) {
    float mu = statN(stats7, tid) * INV11, q = statN(stats7, 10 + tid) * INV11;
    float isd = rsqrtf(q - mu * mu + EPSV);
    float s = gs[tid] * isd;
    sc[tid] = s;
    sh[tid] = bs[tid] - mu * s;
  }
  __syncthreads();
  for (int p = tid; p < 121; p += 256) {
    const _Float16* rp = T7 + ((long)img * 121 + p) * 40;
#pragma unroll
    for (int cg5 = 0; cg5 < 5; ++cg5) {
      v8h v = *(const v8h*)(rp + cg5 * 8);
#pragma unroll
      for (int fh = 0; fh < 2; ++fh) {
        const int f = cg5 * 2 + fh;
        float mx = fmaf((float)v[fh * 4], sc[f], sh[f]);
#pragma unroll
        for (int r = 1; r < 4; ++r)
          mx = fmaxf(mx, fmaf((float)v[fh * 4 + r], sc[f], sh[f]));
        mbuf[f * 121 + p] = fmaxf(0.f, mx);
      }
    }
  }
  __syncthreads();
  const int wv = tid >> 6;
  for (int k = 0; k < 10; ++k) {
    float p = 0.f;
    for (int j = tid; j < 1210; j += 256) p = fmaf(mbuf[j], wfc[k * 1210 + j], p);
#pragma unroll
    for (int off = 32; off > 0; off >>= 1) p += __shfl_xor(p, off, 64);
    if ((tid & 63) == 0) red[k * 4 + wv] = p;
  }
  __syncthreads();
  if (tid < 10)
    out[img * 10 + tid] = bfc[tid] + red[tid * 4] + red[tid * 4 + 1] +
                          red[tid * 4 + 2] + red[tid * 4 + 3];
}

extern "C" void kernel_launch(void* const* d_in, const int* in_sizes, int n_in,
                              void* d_out, int out_size, void* d_ws, size_t ws_size,
                              hipStream_t stream) {
  const float* x   = (const float*)d_in[0];
  const float* w1  = (const float*)d_in[1];
  const float* w2  = (const float*)d_in[2];
  const float* w3  = (const float*)d_in[3];
  const float* w4  = (const float*)d_in[4];
  const float* w5  = (const float*)d_in[5];
  const float* w6  = (const float*)d_in[6];
  const float* w7  = (const float*)d_in[7];
  const float* g1  = (const float*)d_in[8];
  const float* b1  = (const float*)d_in[9];
  const float* g2  = (const float*)d_in[10];
  const float* b2  = (const float*)d_in[11];
  const float* gs  = (const float*)d_in[12];
  const float* bs  = (const float*)d_in[13];
  const float* wfc = (const float*)d_in[14];
  const float* bfc = (const float*)d_in[15];

  float* ws = (float*)d_ws;
  // Workspace (floats), ~31.1 MB (in-place tail, no ping-pong buffer):
  float* stats  = ws;                          // 7 layers x NCOPY(8) x 32 = 1792
  _Float16* K1h = (_Float16*)(ws + 1792);      // 1536 fp16 (conv1 MFMA A-table)
  _Float16* Wh  = (_Float16*)(ws + 2560);      // 122,880 fp16 -> ends 64000
  _Float16* T0  = (_Float16*)(ws + 64000);     // tile [1024][256][40] fp16 -> ends 5306880
  _Float16* T7  = (_Float16*)(ws + 5306880L);  // conv7 raw [1024][121][40] fp16

  // zero BN stats via memset node (replaces the prep->conv1_stats boundary)
  hipMemsetAsync(stats, 0, 7 * LSTRIDE * sizeof(float), stream);
  // merged: weight tables (blocks 0..485) + conv1 stats (blocks 486..1509)
  prep_stats<<<1510, 256, 0, stream>>>(x, w1, w2, w3, w4, w5, w6, w7,
                                       K1h, Wh, stats);
  // conv2 (conv1 fused in staging): all R=4 bands, in-register pooled raw -> T0
  conv_band_all<<<7168, 256, 0, stream>>>(x, K1h, Wh, stats, g1, b1, T0,
                                          stats + LSTRIDE);
  // conv3..conv6 in place on T0
  conv_tile<<<1024, 256, 0, stream>>>(T0, Wh + 18432, stats + LSTRIDE, g2, b2, INV28,
                                      stats + 2 * LSTRIDE);
  conv_tile<<<1024, 256, 0, stream>>>(T0, Wh + 36864, stats + 2 * LSTRIDE, gs, bs, INV14,
                                      stats + 3 * LSTRIDE);
  conv_tile<<<1024, 256, 0, stream>>>(T0, Wh + 55296, stats + 3 * LSTRIDE, gs, bs, INV14,
                                      stats + 4 * LSTRIDE);
  conv_tile<<<1024, 256, 0, stream>>>(T0, Wh + 73728, stats + 4 * LSTRIDE, gs, bs, INV14,
                                      stats + 5 * LSTRIDE);
  // conv7
  conv7_tile<<<1024, 256, 0, stream>>>(T0, Wh + 92160, stats + 5 * LSTRIDE, gs, bs,
                                       T7, stats + 6 * LSTRIDE);
  // head
  head_kernel<<<1024, 256, 0, stream>>>(T7, stats + 6 * LSTRIDE, gs, bs, wfc, bfc,
                                        (float*)d_out);
}